// Round 1
// baseline (41.952 us; speedup 1.0000x reference)
//
#include <hip/hip_runtime.h>
#include <math.h>

#define N_TOK 2048
#define P_DIM 16
#define F_DIM 32
#define H_DIM 16
#define D_DIM 64
#define D2    32

// ---------------------------------------------------------------------------
// Kernel 1: one block per row i.
//   Phase 1: cooperative dist[i, j] for all j into LDS (8 KB).
//   Phase 2: f = tid&31, 8 groups of 32 lanes each sweep 256 j's, accumulate
//            sin(dist * freq[f]); LDS reduce across groups -> sin_node[i][f].
// ---------------------------------------------------------------------------
__global__ __launch_bounds__(256) void sin_node_kernel(
    const float* __restrict__ positions,   // (N, P)
    const float* __restrict__ log_freqs,   // (F)
    float* __restrict__ sin_node)          // (N, F)  in workspace
{
    __shared__ float s_dist[N_TOK];
    __shared__ float s_red[8][F_DIM];

    const int i   = blockIdx.x;
    const int tid = threadIdx.x;

    // positions[i][*] -> registers (broadcast load, L2-hot)
    float pi[P_DIM];
#pragma unroll
    for (int p = 0; p < P_DIM; p += 4) {
        float4 v = *reinterpret_cast<const float4*>(&positions[i * P_DIM + p]);
        pi[p] = v.x; pi[p + 1] = v.y; pi[p + 2] = v.z; pi[p + 3] = v.w;
    }

    // Phase 1: each thread computes 8 distances
    for (int j = tid; j < N_TOK; j += 256) {
        float s = 0.f;
#pragma unroll
        for (int p = 0; p < P_DIM; p += 4) {
            float4 v = *reinterpret_cast<const float4*>(&positions[j * P_DIM + p]);
            float d0 = pi[p]     - v.x;
            float d1 = pi[p + 1] - v.y;
            float d2 = pi[p + 2] - v.z;
            float d3 = pi[p + 3] - v.w;
            s += d0 * d0 + d1 * d1 + d2 * d2 + d3 * d3;
        }
        s_dist[j] = sqrtf(fmaxf(s, 1e-12f));
    }
    __syncthreads();

    // Phase 2: 134M sins device-wide is the hot loop
    const int   f    = tid & 31;
    const int   grp  = tid >> 5;
    const float freq = __expf(log_freqs[f]);

    float acc = 0.f;
    const int j0 = grp * 256;
#pragma unroll 4
    for (int j = j0; j < j0 + 256; ++j) {
        acc += __sinf(s_dist[j] * freq);   // LDS broadcast read per 32-lane group
    }
    s_red[grp][f] = acc;
    __syncthreads();

    if (tid < F_DIM) {
        float t = 0.f;
#pragma unroll
        for (int g = 0; g < 8; ++g) t += s_red[g][tid];
        sin_node[i * F_DIM + tid] = t * (1.0f / (float)N_TOK);
    }
}

// ---------------------------------------------------------------------------
// Kernel 2: streaming rotate. Thread = (n, h, f4) handles 4 consecutive freqs
// for BOTH q and k. cos_node = cos(1e-6 * freq) (diag(dist) == 1e-6 exactly).
// ---------------------------------------------------------------------------
__global__ __launch_bounds__(256) void rope_apply_kernel(
    const float* __restrict__ q,           // (N, H, D)
    const float* __restrict__ k,           // (N, H, D)
    const float* __restrict__ log_freqs,   // (F)
    const float* __restrict__ sin_node,    // (N, F)
    float* __restrict__ out)               // q_rot (N,H,D) then k_rot (N,H,D)
{
    const int idx = blockIdx.x * 256 + threadIdx.x;     // 0 .. N*H*8-1
    const int f4  = (idx & 7) * 4;
    const int nh  = idx >> 3;                           // n*H + h
    const int n   = nh >> 4;                            // / H

    // cos_node (constant per f; diag dist == 1e-6)
    const float4 lf = *reinterpret_cast<const float4*>(&log_freqs[f4]);
    float4 c;
    c.x = cosf(1e-6f * __expf(lf.x));
    c.y = cosf(1e-6f * __expf(lf.y));
    c.z = cosf(1e-6f * __expf(lf.z));
    c.w = cosf(1e-6f * __expf(lf.w));

    const float4 s = *reinterpret_cast<const float4*>(&sin_node[n * F_DIM + f4]);

    const int base = nh * D_DIM + f4;
    const int NHD  = N_TOK * H_DIM * D_DIM;

    // q
    {
        float4 a = *reinterpret_cast<const float4*>(&q[base]);
        float4 b = *reinterpret_cast<const float4*>(&q[base + D2]);
        float4 r1, r2;
        r1.x = a.x * c.x - b.x * s.x;  r2.x = a.x * s.x + b.x * c.x;
        r1.y = a.y * c.y - b.y * s.y;  r2.y = a.y * s.y + b.y * c.y;
        r1.z = a.z * c.z - b.z * s.z;  r2.z = a.z * s.z + b.z * c.z;
        r1.w = a.w * c.w - b.w * s.w;  r2.w = a.w * s.w + b.w * c.w;
        *reinterpret_cast<float4*>(&((float*)out)[base])      = r1;
        *reinterpret_cast<float4*>(&((float*)out)[base + D2]) = r2;
    }
    // k
    {
        float4 a = *reinterpret_cast<const float4*>(&k[base]);
        float4 b = *reinterpret_cast<const float4*>(&k[base + D2]);
        float4 r1, r2;
        r1.x = a.x * c.x - b.x * s.x;  r2.x = a.x * s.x + b.x * c.x;
        r1.y = a.y * c.y - b.y * s.y;  r2.y = a.y * s.y + b.y * c.y;
        r1.z = a.z * c.z - b.z * s.z;  r2.z = a.z * s.z + b.z * c.z;
        r1.w = a.w * c.w - b.w * s.w;  r2.w = a.w * s.w + b.w * c.w;
        float* o = (float*)out + NHD;
        *reinterpret_cast<float4*>(&o[base])      = r1;
        *reinterpret_cast<float4*>(&o[base + D2]) = r2;
    }
}

extern "C" void kernel_launch(void* const* d_in, const int* in_sizes, int n_in,
                              void* d_out, int out_size, void* d_ws, size_t ws_size,
                              hipStream_t stream) {
    const float* q         = (const float*)d_in[0];
    const float* k         = (const float*)d_in[1];
    const float* positions = (const float*)d_in[2];
    const float* log_freqs = (const float*)d_in[3];

    float* sin_node = (float*)d_ws;                   // N*F floats = 256 KB
    float* out      = (float*)d_out;

    sin_node_kernel<<<N_TOK, 256, 0, stream>>>(positions, log_freqs, sin_node);

    const int total2 = N_TOK * H_DIM * 8;             // threads for apply
    rope_apply_kernel<<<total2 / 256, 256, 0, stream>>>(q, k, log_freqs, sin_node, out);
}

// Round 2
// 34.520 us; speedup vs baseline: 1.2153x; 1.2153x over previous
//
#include <hip/hip_runtime.h>
#include <math.h>

#define N_TOK 2048
#define P_DIM 16
#define F_DIM 32
#define H_DIM 16
#define D_DIM 64
#define D2    32
#define TI    2          // rows of the dist matrix per block

// ---------------------------------------------------------------------------
// Kernel 1: block handles TI=2 rows i.
//   Phase 1: cooperative dist[r, j] for all j into LDS (TI*8 KB).
//   Phase 2: thread owns 4 freqs (f0=(tid&7)*4) and j-stripe grp=tid>>3;
//            per LDS read of d it does 4 sins  ->  8 sins per 2 reads.
//   j = grp + 32*it puts the wave's 8 distinct addresses in 8 distinct banks
//   (broadcast within each 8-lane group).
// ---------------------------------------------------------------------------
__global__ __launch_bounds__(256) void sin_node_kernel(
    const float* __restrict__ positions,   // (N, P)
    const float* __restrict__ log_freqs,   // (F)
    float* __restrict__ sin_node)          // (N, F)  in workspace
{
    __shared__ float s_dist[TI][N_TOK];          // 16 KB
    __shared__ float s_red[32][TI][F_DIM];       //  8 KB

    const int tid = threadIdx.x;
    const int r0  = blockIdx.x * TI;

    // positions for the TI rows -> registers (L2-hot broadcast)
    float pr[TI][P_DIM];
#pragma unroll
    for (int r = 0; r < TI; ++r)
#pragma unroll
        for (int p = 0; p < P_DIM; p += 4) {
            float4 v = *reinterpret_cast<const float4*>(&positions[(r0 + r) * P_DIM + p]);
            pr[r][p] = v.x; pr[r][p+1] = v.y; pr[r][p+2] = v.z; pr[r][p+3] = v.w;
        }

    // Phase 1: 8 j's per thread, both rows per position load
    for (int j = tid; j < N_TOK; j += 256) {
        float s[TI] = {};
#pragma unroll
        for (int p = 0; p < P_DIM; p += 4) {
            float4 v = *reinterpret_cast<const float4*>(&positions[j * P_DIM + p]);
#pragma unroll
            for (int r = 0; r < TI; ++r) {
                float d0 = pr[r][p]   - v.x;
                float d1 = pr[r][p+1] - v.y;
                float d2 = pr[r][p+2] - v.z;
                float d3 = pr[r][p+3] - v.w;
                s[r] += d0*d0 + d1*d1 + d2*d2 + d3*d3;
            }
        }
#pragma unroll
        for (int r = 0; r < TI; ++r)
            s_dist[r][j] = sqrtf(fmaxf(s[r], 1e-12f));
    }
    __syncthreads();

    // Phase 2: the transcendental hot loop
    const int f0  = (tid & 7) * 4;
    const int grp = tid >> 3;                    // 0..31
    float fr[4];
#pragma unroll
    for (int u = 0; u < 4; ++u) fr[u] = __expf(log_freqs[f0 + u]);

    float acc[TI][4] = {};
#pragma unroll 4
    for (int it = 0; it < N_TOK / 32; ++it) {
        const int j = grp + it * 32;
        const float d0 = s_dist[0][j];
        const float d1 = s_dist[1][j];
#pragma unroll
        for (int u = 0; u < 4; ++u) {
            acc[0][u] += __sinf(d0 * fr[u]);
            acc[1][u] += __sinf(d1 * fr[u]);
        }
    }
#pragma unroll
    for (int u = 0; u < 4; ++u) {
        s_red[grp][0][f0 + u] = acc[0][u];
        s_red[grp][1][f0 + u] = acc[1][u];
    }
    __syncthreads();

    if (tid < TI * F_DIM) {
        const int row = tid >> 5, f = tid & 31;
        float t = 0.f;
#pragma unroll
        for (int g = 0; g < 32; ++g) t += s_red[g][row][f];
        sin_node[(r0 + row) * F_DIM + f] = t * (1.0f / (float)N_TOK);
    }
}

// ---------------------------------------------------------------------------
// Kernel 2: streaming rotate. Thread = (n, h, f4) handles 4 consecutive freqs
// for BOTH q and k. cos_node = cos(1e-6 * freq) (diag(dist) == 1e-6 exactly).
// ---------------------------------------------------------------------------
__global__ __launch_bounds__(256) void rope_apply_kernel(
    const float* __restrict__ q,           // (N, H, D)
    const float* __restrict__ k,           // (N, H, D)
    const float* __restrict__ log_freqs,   // (F)
    const float* __restrict__ sin_node,    // (N, F)
    float* __restrict__ out)               // q_rot (N,H,D) then k_rot (N,H,D)
{
    const int idx = blockIdx.x * 256 + threadIdx.x;     // 0 .. N*H*8-1
    const int f4  = (idx & 7) * 4;
    const int nh  = idx >> 3;                           // n*H + h
    const int n   = nh >> 4;                            // / H

    const float4 lf = *reinterpret_cast<const float4*>(&log_freqs[f4]);
    float4 c;
    c.x = cosf(1e-6f * __expf(lf.x));
    c.y = cosf(1e-6f * __expf(lf.y));
    c.z = cosf(1e-6f * __expf(lf.z));
    c.w = cosf(1e-6f * __expf(lf.w));

    const float4 s = *reinterpret_cast<const float4*>(&sin_node[n * F_DIM + f4]);

    const int base = nh * D_DIM + f4;
    const int NHD  = N_TOK * H_DIM * D_DIM;

    {
        float4 a = *reinterpret_cast<const float4*>(&q[base]);
        float4 b = *reinterpret_cast<const float4*>(&q[base + D2]);
        float4 r1, r2;
        r1.x = a.x*c.x - b.x*s.x;  r2.x = a.x*s.x + b.x*c.x;
        r1.y = a.y*c.y - b.y*s.y;  r2.y = a.y*s.y + b.y*c.y;
        r1.z = a.z*c.z - b.z*s.z;  r2.z = a.z*s.z + b.z*c.z;
        r1.w = a.w*c.w - b.w*s.w;  r2.w = a.w*s.w + b.w*c.w;
        *reinterpret_cast<float4*>(&((float*)out)[base])      = r1;
        *reinterpret_cast<float4*>(&((float*)out)[base + D2]) = r2;
    }
    {
        float4 a = *reinterpret_cast<const float4*>(&k[base]);
        float4 b = *reinterpret_cast<const float4*>(&k[base + D2]);
        float4 r1, r2;
        r1.x = a.x*c.x - b.x*s.x;  r2.x = a.x*s.x + b.x*c.x;
        r1.y = a.y*c.y - b.y*s.y;  r2.y = a.y*s.y + b.y*c.y;
        r1.z = a.z*c.z - b.z*s.z;  r2.z = a.z*s.z + b.z*c.z;
        r1.w = a.w*c.w - b.w*s.w;  r2.w = a.w*s.w + b.w*c.w;
        float* o = (float*)out + NHD;
        *reinterpret_cast<float4*>(&o[base])      = r1;
        *reinterpret_cast<float4*>(&o[base + D2]) = r2;
    }
}

extern "C" void kernel_launch(void* const* d_in, const int* in_sizes, int n_in,
                              void* d_out, int out_size, void* d_ws, size_t ws_size,
                              hipStream_t stream) {
    const float* q         = (const float*)d_in[0];
    const float* k         = (const float*)d_in[1];
    const float* positions = (const float*)d_in[2];
    const float* log_freqs = (const float*)d_in[3];

    float* sin_node = (float*)d_ws;                   // N*F floats = 256 KB
    float* out      = (float*)d_out;

    sin_node_kernel<<<N_TOK / TI, 256, 0, stream>>>(positions, log_freqs, sin_node);

    const int total2 = N_TOK * H_DIM * 8;
    rope_apply_kernel<<<total2 / 256, 256, 0, stream>>>(q, k, log_freqs, sin_node, out);
}